// Round 6
// baseline (139.909 us; speedup 1.0000x reference)
//
#include <hip/hip_runtime.h>
#include <hip/hip_fp16.h>

// Problem constants (from reference) — ALL TENSORS ARE FLOAT32.
#define B_    1024
#define N_    256
#define E_    2304      // == 9 * 256 exactly
#define EPT_  9         // edges per thread in CSR build
#define FIN_  6
#define VEC_  26
#define STR_  36        // f32 LDS row stride (144 B, 16B-aligned -> ds_read_b128)

// ---------------------------------------------------------------------------
// Single fused kernel: one block per batch element; 256 threads = 1 thread/node.
// Each block redundantly builds the tiny shared CSR (+norms, +degree-sorted
// perm) in LDS, then runs 3 gconv layers in LDS, mean-pool, emb, fused head.
// Compute body is the verified round-5 f32 code.
// ---------------------------------------------------------------------------
__global__ __launch_bounds__(256) void fused_kernel(
    const float* __restrict__ gf,    // [B,N,6]
    const float* __restrict__ vec,   // [B,26]
    const int* __restrict__ src, const int* __restrict__ dst,
    const float* __restrict__ W1, const float* __restrict__ b1,   // [6,32],[32]
    const float* __restrict__ W2, const float* __restrict__ b2,   // [32,32]
    const float* __restrict__ W3, const float* __restrict__ b3,
    const float* __restrict__ We, const float* __restrict__ be,   // [32,32]
    const float* __restrict__ Wpi, const float* __restrict__ bpi, // [58,512],[512]
    const float* __restrict__ Wvf, const float* __restrict__ bvf,
    float2* __restrict__ out)        // f32 pairs; pi @ [0,262144), vf @ +262144
{
    __shared__ __align__(16) float buf[N_ * STR_];   // 36,864 B: per-node h rows
    __shared__ unsigned int packedE[E_];             //  9,216 B: (src<<16)|f16(norm)
    __shared__ float part[8 * 33];
    __shared__ float hgl[32];
    __shared__ float comb[VEC_ + 32];

    const int t = threadIdx.x;
    const int b = blockIdx.x;

    // ---- CSR scratch overlaid on buf (fully consumed before staging) ----
    int*   deg_o  = (int*)buf;          // [256]
    int*   deg_i  = (int*)buf + 256;    // [256]
    int*   scan   = (int*)buf + 512;    // [256]  (inclusive scan of deg_i)
    int*   cursor = (int*)buf + 768;    // [256]
    int*   bcnt   = (int*)buf + 1024;   // [64]
    int*   boff   = (int*)buf + 1088;   // [64]
    int*   perm   = (int*)buf + 1152;   // [256]
    float* inv_o  = buf + 1408;         // [256]
    float* inv_i  = buf + 1664;         // [256]

    // ================= per-block CSR build =================
    deg_o[t] = 0; deg_i[t] = 0;
    if (t < 64) bcnt[t] = 0;
    __syncthreads();

    int sB[EPT_], dB[EPT_];
#pragma unroll
    for (int i = 0; i < EPT_; ++i) {
        int e = t + 256 * i;
        sB[i] = src[e]; dB[i] = dst[e];
    }
#pragma unroll
    for (int i = 0; i < EPT_; ++i) {
        atomicAdd(&deg_o[sB[i]], 1);
        atomicAdd(&deg_i[dB[i]], 1);
    }
    __syncthreads();

    const int dI = deg_i[t];
    {
        int dO = deg_o[t];
        inv_o[t] = dO > 0 ? rsqrtf((float)dO) : 0.f;
        inv_i[t] = dI > 0 ? rsqrtf((float)dI) : 0.f;
        scan[t] = dI;
    }
    __syncthreads();
    // Hillis-Steele inclusive scan of deg_i
    for (int off = 1; off < N_; off <<= 1) {
        int v = (t >= off) ? scan[t - off] : 0;
        __syncthreads();
        scan[t] += v;
        __syncthreads();
    }
    cursor[t] = scan[t] - dI;                 // exclusive start for node t
    int dmy = dI > 63 ? 63 : dI;
    atomicAdd(&bcnt[dmy], 1);
    __syncthreads();
    if (t == 0) { int run = 0; for (int i = 0; i < 64; ++i) { boff[i] = run; run += bcnt[i]; } }
    __syncthreads();
    { int pos = atomicAdd(&boff[dmy], 1); perm[pos] = t; }
    // scatter edges into dst-sorted CSR; norm packed as f16 in low half
#pragma unroll
    for (int i = 0; i < EPT_; ++i) {
        int s = sB[i], d = dB[i];
        int pos = atomicAdd(&cursor[d], 1);
        float nrm = inv_o[s] * inv_i[d];
        unsigned short h = __half_as_ushort(__float2half(nrm));
        packedE[pos] = ((unsigned int)s << 16) | (unsigned int)h;
    }
    __syncthreads();

    const int node = perm[t];                 // degree-sorted node assignment
    const int end  = scan[node];
    const int beg  = end - deg_i[node];
    __syncthreads();                          // scratch reads done; buf reusable

    // ================= stage node features (pad cols 6,7 = 0) =============
    {
        const float* g = gf + (size_t)b * (N_ * FIN_);
        for (int i = t; i < N_ * 8; i += 256) {
            int n = i >> 3, k = i & 7;
            buf[n * STR_ + k] = (k < FIN_) ? g[n * FIN_ + k] : 0.f;
        }
    }
    __syncthreads();

    float o[32];

    // ================= layer 1: gather (2x float4) + [6x32] GEMM + relu ====
    {
        float a[8] = {0,0,0,0,0,0,0,0};
        for (int e = beg; e < end; ++e) {
            unsigned int u = packedE[e];
            float w = __half2float(__ushort_as_half((unsigned short)(u & 0xffffu)));
            const float4* hr = (const float4*)&buf[(u >> 16) * STR_];
            float4 c0 = hr[0], c1 = hr[1];
            a[0] += w * c0.x; a[1] += w * c0.y; a[2] += w * c0.z; a[3] += w * c0.w;
            a[4] += w * c1.x; a[5] += w * c1.y;
        }
#pragma unroll
        for (int j = 0; j < 32; ++j) o[j] = b1[j];
#pragma unroll
        for (int k = 0; k < FIN_; ++k) {
            float ak = a[k];
            const float* wr = &W1[k * 32];
#pragma unroll
            for (int j = 0; j < 32; ++j) o[j] += ak * wr[j];
        }
#pragma unroll
        for (int j = 0; j < 32; ++j) o[j] = fmaxf(o[j], 0.f);
    }
    __syncthreads();
    {
        float4* row = (float4*)&buf[node * STR_];
#pragma unroll
        for (int q = 0; q < 8; ++q) row[q] = make_float4(o[4*q], o[4*q+1], o[4*q+2], o[4*q+3]);
    }
    __syncthreads();

    // ================= layers 2 & 3: gather(8x float4) + [32x32] GEMM ======
    for (int L = 0; L < 2; ++L) {
        float acc[32];
#pragma unroll
        for (int k = 0; k < 32; ++k) acc[k] = 0.f;
        for (int e = beg; e < end; ++e) {
            unsigned int u = packedE[e];
            float w = __half2float(__ushort_as_half((unsigned short)(u & 0xffffu)));
            const float4* hr = (const float4*)&buf[(u >> 16) * STR_];
#pragma unroll
            for (int q = 0; q < 8; ++q) {
                float4 c = hr[q];
                acc[4*q]   += w * c.x;
                acc[4*q+1] += w * c.y;
                acc[4*q+2] += w * c.z;
                acc[4*q+3] += w * c.w;
            }
        }
        const float* Wl = (L == 0) ? W2 : W3;
        const float* Bl = (L == 0) ? b2 : b3;
#pragma unroll
        for (int j = 0; j < 32; ++j) o[j] = Bl[j];
#pragma unroll 8
        for (int k = 0; k < 32; ++k) {
            float ak = acc[k];
            const float* wr = &Wl[k * 32];
#pragma unroll
            for (int j = 0; j < 32; ++j) o[j] += ak * wr[j];
        }
#pragma unroll
        for (int j = 0; j < 32; ++j) o[j] = fmaxf(o[j], 0.f);
        __syncthreads();
        {
            float4* row = (float4*)&buf[node * STR_];
#pragma unroll
            for (int q = 0; q < 8; ++q) row[q] = make_float4(o[4*q], o[4*q+1], o[4*q+2], o[4*q+3]);
        }
        __syncthreads();
    }

    // ================= mean over nodes -> hg[32] ===========================
    {
        int j = t & 31, g = t >> 5;
        float s = 0.f;
        for (int i = 0; i < 32; ++i) s += buf[(g * 32 + i) * STR_ + j];
        part[g * 33 + j] = s;
    }
    __syncthreads();
    if (t < 32) {
        float sum = 0.f;
#pragma unroll
        for (int g = 0; g < 8; ++g) sum += part[g * 33 + t];
        hgl[t] = sum * (1.0f / 256.0f);
    }
    __syncthreads();

    // ================= emb + comb ==========================================
    if (t < 32) {
        float v = be[t];
#pragma unroll
        for (int j = 0; j < 32; ++j) v += hgl[j] * We[j * 32 + t];
        comb[VEC_ + t] = v;
    }
    if (t < VEC_) comb[t] = vec[b * VEC_ + t];
    __syncthreads();

    // ================= head: thread t -> pi/vf outputs 2t, 2t+1 ============
    {
        float p0 = bpi[2 * t], p1 = bpi[2 * t + 1];
        float v0 = bvf[2 * t], v1 = bvf[2 * t + 1];
        const float2* Wp = (const float2*)Wpi;   // [58][256] float2
        const float2* Wv = (const float2*)Wvf;
        for (int k = 0; k < VEC_ + 32; ++k) {
            float c = comb[k];
            float2 a = Wp[k * 256 + t];
            p0 += c * a.x; p1 += c * a.y;
            float2 d = Wv[k * 256 + t];
            v0 += c * d.x; v1 += c * d.y;
        }
        out[b * 256 + t]          = make_float2(fmaxf(p0, 0.f), fmaxf(p1, 0.f));
        out[262144 + b * 256 + t] = make_float2(fmaxf(v0, 0.f), fmaxf(v1, 0.f));
    }
}

extern "C" void kernel_launch(void* const* d_in, const int* in_sizes, int n_in,
                              void* d_out, int out_size, void* d_ws, size_t ws_size,
                              hipStream_t stream)
{
    // d_in order: 0 gf, 1 vec, 2 src, 3 dst, 4 W1, 5 b1, 6 W2, 7 b2, 8 W3, 9 b3,
    //             10 W_emb, 11 b_emb, 12 W_pi, 13 b_pi, 14 W_vf, 15 b_vf
    fused_kernel<<<B_, 256, 0, stream>>>(
        (const float*)d_in[0], (const float*)d_in[1],
        (const int*)d_in[2], (const int*)d_in[3],
        (const float*)d_in[4], (const float*)d_in[5],
        (const float*)d_in[6], (const float*)d_in[7],
        (const float*)d_in[8], (const float*)d_in[9],
        (const float*)d_in[10], (const float*)d_in[11],
        (const float*)d_in[12], (const float*)d_in[13],
        (const float*)d_in[14], (const float*)d_in[15],
        (float2*)d_out);
}